// Round 7
// baseline (379.205 us; speedup 1.0000x reference)
//
#include <hip/hip_runtime.h>
#include <stdint.h>

#define ROWS 150528              // 1024 * 147
#define QSCALE 0.17677669529663687f
#define L2E 1.44269504088896f

typedef __attribute__((ext_vector_type(8))) __bf16 bf16x8;
typedef __attribute__((ext_vector_type(4))) __bf16 bf16x4;
typedef __attribute__((ext_vector_type(4))) float f32x4;
typedef __attribute__((ext_vector_type(4))) float f4;

static __device__ __forceinline__ f32x4 mfma_bf16(bf16x8 a, bf16x8 b, f32x4 c) {
  return __builtin_amdgcn_mfma_f32_16x16x32_bf16(a, b, c, 0, 0, 0);
}

static __device__ __forceinline__ uint32_t pack_bf16(float a, float b) {
  uint16_t ux = __builtin_bit_cast(uint16_t, (__bf16)a);
  uint16_t uy = __builtin_bit_cast(uint16_t, (__bf16)b);
  return (uint32_t)ux | ((uint32_t)uy << 16);
}

// ---- convert 4 f32 weights -> bf16 in one launch: grid (36, 4) ----
__global__ void cvt4(const float* s0, const float* s1, const float* s2, const float* s3,
                     __bf16* d0, __bf16* d1, __bf16* d2, __bf16* d3) {
  const int y = blockIdx.y;
  const float* s = y == 0 ? s0 : y == 1 ? s1 : y == 2 ? s2 : s3;
  __bf16* d = y == 0 ? d0 : y == 1 ? d1 : y == 2 ? d2 : d3;
  int i = blockIdx.x * 256 + threadIdx.x;        // 9216 float4 groups
  f4 v = ((const f4*)s)[i];
  bf16x4 b;
  b[0] = (__bf16)v[0]; b[1] = (__bf16)v[1]; b[2] = (__bf16)v[2]; b[3] = (__bf16)v[3];
  ((bf16x4*)d)[i] = b;
}

// ---- precompute l2e*(mask+bias) in exact per-lane access order ----
// bmw[(win*6+h)*7840 + q49*160 + key], key = 32s+8lg+j in [0,160); value uses
// k49 = key % 49. In-kernel lane (s,lg) reads 8 consecutive f32 (32B aligned).
__global__ void bmpre(const float* __restrict__ maskp, const float* __restrict__ btab,
                      float* __restrict__ bmw) {
  const int win = blockIdx.x, h = blockIdx.y;
  __shared__ float msk[2401];
  __shared__ float bt[169];
  for (int i = threadIdx.x; i < 2401; i += 256) msk[i] = maskp[win * 2401 + i];
  for (int i = threadIdx.x; i < 169; i += 256) bt[i] = btab[i * 6 + h];
  __syncthreads();
  float* dst = bmw + (size_t)(win * 6 + h) * 7840;
  for (int o = threadIdx.x; o < 7840; o += 256) {
    int q49 = o / 160, key = o - q49 * 160;
    int k49 = key;                                  // key % 49 (key <= 159)
    if (k49 >= 98) k49 -= 98; else if (k49 >= 49) k49 -= 49;
    if (k49 >= 49) k49 -= 49;
    int qi = q49 / 7, qj = q49 - qi * 7, ki = k49 / 7, kj = k49 - ki * 7;
    int rel = (qi - ki + 6) * 13 + (qj - kj + 6);
    dst[o] = (msk[q49 * 49 + k49] + bt[rel]) * L2E;
  }
}

// ---- GEMM v3: t-outer (wf[6] live only), head-major bf16 side buffers ----
// IN_F32: X row-major f32 [M][192]; else head-major bf16 [6][ROWS][32].
// OUT_F32: O row-major f32 [M][192]; else head-major bf16 [6][ROWS][32].
template<bool IN_F32, bool OUT_F32>
__global__ __launch_bounds__(256, 3)
void gemmv3(const void* __restrict__ Xv, const __bf16* __restrict__ Wb,
            const float* __restrict__ bias, void* __restrict__ Ov, float scale)
{
  __shared__ __align__(16) __bf16 Xs[64 * 200];   // pad 192->200
  const int tid = threadIdx.x;
  const int wv = tid >> 6, lane = tid & 63, lr = lane & 15, lg = lane >> 4;
  const size_t row0 = (size_t)blockIdx.x * 64;

  if (IN_F32) {
    const f4* X4 = (const f4*)Xv + row0 * 48;
    #pragma unroll
    for (int p = 0; p < 12; ++p) {
      int i = tid + p * 256;
      int r = i / 48, c = i % 48;
      f4 v = X4[i];
      bf16x4 bb;
      bb[0] = (__bf16)v[0]; bb[1] = (__bf16)v[1]; bb[2] = (__bf16)v[2]; bb[3] = (__bf16)v[3];
      *(bf16x4*)&Xs[r * 200 + c * 4] = bb;
    }
  } else {
    const __bf16* X = (const __bf16*)Xv;
    #pragma unroll
    for (int p = 0; p < 6; ++p) {
      int i = tid + p * 256;                       // 64 rows x 24 c8
      int r = i / 24, c8 = i % 24;
      int hh = c8 >> 2, sub = c8 & 3;
      *(bf16x8*)&Xs[r * 200 + c8 * 8] =
          *(const bf16x8*)&X[((size_t)hh * ROWS + row0 + r) * 32 + sub * 8];
    }
  }
  __syncthreads();

  #pragma unroll
  for (int t = 0; t < 3; ++t) {
    const int nt = wv + 4 * t;
    bf16x8 wf[6];
    const __bf16* wr = &Wb[(nt * 16 + lr) * 192 + lg * 8];
    #pragma unroll
    for (int kk = 0; kk < 6; ++kk) wf[kk] = *(const bf16x8*)&wr[kk * 32];
    const float bcol = bias[nt * 16 + lr] * scale;

    #pragma unroll
    for (int rg = 0; rg < 4; ++rg) {
      bf16x8 a[6];
      const __bf16* xr = &Xs[(rg * 16 + lr) * 200 + lg * 8];
      #pragma unroll
      for (int kk = 0; kk < 6; ++kk) a[kk] = *(const bf16x8*)&xr[kk * 32];
      f32x4 acc = {0.f, 0.f, 0.f, 0.f};
      #pragma unroll
      for (int kk = 0; kk < 6; ++kk) acc = mfma_bf16(a[kk], wf[kk], acc);
      const size_t grow = row0 + rg * 16 + lg * 4;
      if (OUT_F32) {
        const int col = nt * 16 + lr;
        #pragma unroll
        for (int j = 0; j < 4; ++j)
          ((float*)Ov)[(grow + j) * 192 + col] = acc[j] * scale + bcol;
      } else {
        const int hh = nt >> 1, c32 = (nt & 1) * 16 + lr;
        #pragma unroll
        for (int j = 0; j < 4; ++j)
          ((__bf16*)Ov)[((size_t)hh * ROWS + grow + j) * 32 + c32] =
              (__bf16)(acc[j] * scale + bcol);
      }
    }
  }
}

// ---- attention v7: head-major I/O, bm from global (aligned f4), 23.5KB LDS ----
// key(kt,4lg+j) = (kt>>1)*32 + lg*8 + (kt&1)*4 + j; Ks staged at permuted rows.
// Per s-step: kt-pair {2s,2s+1} = PV step s's A-fragment -> only st0,st1 live.
__global__ __launch_bounds__(256, 4)
void attn7(const __bf16* __restrict__ Q, const __bf16* __restrict__ K,
           const __bf16* __restrict__ V, __bf16* __restrict__ O,
           const float* __restrict__ bmw)
{
  __shared__ __align__(16) __bf16 Ks[160 * 40];   // 12800 B, permuted rows
  __shared__ __align__(16) __bf16 Vt[32 * 168];   // 10752 B, [d][key pad168]

  const int b = blockIdx.x, h = blockIdx.y;
  const int tid = threadIdx.x;
  const size_t hb = (size_t)h * ROWS + (size_t)b * 147;  // head-major row base
  const int wv = tid >> 6, lane = tid & 63;
  const int lr = lane & 15, lg = lane >> 4;

  // first Q fragment (mt=wv -> row<64, no clamp)
  bf16x8 qf = *(const bf16x8*)&Q[(hb + wv * 16 + lr) * 32 + lg * 8];

  // ---- staging (global reads fully contiguous in head-major) ----
  for (int i = tid; i < 588; i += 256) {          // K -> permuted rows
    int k = i >> 2, c = i & 3;
    int phys = (k & ~31) | (((k >> 2) & 1) << 4) | (((k >> 3) & 3) << 2) | (k & 3);
    *(bf16x8*)&Ks[phys * 40 + c * 8] = *(const bf16x8*)&K[(hb + k) * 32 + c * 8];
  }
  for (int t = tid; t < 588; t += 256) {          // V transpose scatter
    int key = t >> 2, dblk = t & 3;
    bf16x8 v = *(const bf16x8*)&V[(hb + key) * 32 + dblk * 8];
    #pragma unroll
    for (int e = 0; e < 8; ++e) Vt[(dblk * 8 + e) * 168 + key] = v[e];
  }
  for (int i = tid; i < 32 * 13; i += 256) {      // zero key tail 147..159
    int d = i / 13, key = 147 + (i - (i / 13) * 13);
    Vt[d * 168 + key] = (__bf16)0.f;
  }
  __syncthreads();

  const f4* bwb = (const f4*)(bmw + (size_t)((b & 63) * 6 + h) * 7840);

  const int nmt = (wv < 2) ? 3 : 2;
  for (int t = 0; t < nmt; ++t) {
    const int mt = wv + 4 * t;

    // prefetch next tile's Q (issued before this tile's stores; per-wave rows disjoint)
    bf16x8 qn = qf;
    if (t + 1 < nmt) {
      int qr = (wv + 4 * (t + 1)) * 16 + lr; if (qr > 146) qr = 146;
      qn = *(const bf16x8*)&Q[(hb + qr) * 32 + lg * 8];
    }

    int r = mt * 16 + lr;
    int q49 = r; if (q49 >= 98) q49 -= 98; if (q49 >= 49) q49 -= 49;
    const f4* bw = bwb + q49 * 40 + lg * 2;        // [s][lg][8] order, 16B aligned

    f32x4 o0 = {0.f,0.f,0.f,0.f}, o1 = {0.f,0.f,0.f,0.f};
    float sum = 0.f;
    #pragma unroll
    for (int s = 0; s < 5; ++s) {
      const f32x4 z = {0.f,0.f,0.f,0.f};
      f32x4 st0 = mfma_bf16(*(const bf16x8*)&Ks[(s * 32 + lr) * 40 + lg * 8], qf, z);
      f32x4 st1 = mfma_bf16(*(const bf16x8*)&Ks[(s * 32 + 16 + lr) * 40 + lg * 8], qf, z);
      const f4 b0 = bw[s * 8];
      const f4 b1 = bw[s * 8 + 1];
      #pragma unroll
      for (int j = 0; j < 4; ++j) { st0[j] += b0[j]; st1[j] += b1[j]; }
      if (s == 4) {                                // keys 128+8lg+j / 132+8lg+j >= 147
        #pragma unroll
        for (int j = 0; j < 4; ++j) {
          if (lg * 8 + j >= 19) st0[j] = -1e30f;
          if (lg * 8 + j >= 15) st1[j] = -1e30f;
        }
      }
      #pragma unroll
      for (int j = 0; j < 4; ++j) { st0[j] = exp2f(st0[j]); sum += st0[j]; }
      #pragma unroll
      for (int j = 0; j < 4; ++j) { st1[j] = exp2f(st1[j]); sum += st1[j]; }
      union { bf16x8 v; uint32_t w[4]; } pu;
      pu.w[0] = pack_bf16(st0[0], st0[1]);
      pu.w[1] = pack_bf16(st0[2], st0[3]);
      pu.w[2] = pack_bf16(st1[0], st1[1]);
      pu.w[3] = pack_bf16(st1[2], st1[3]);
      bf16x8 v0 = *(const bf16x8*)&Vt[lr * 168 + s * 32 + lg * 8];
      bf16x8 v1 = *(const bf16x8*)&Vt[(16 + lr) * 168 + s * 32 + lg * 8];
      o0 = mfma_bf16(pu.v, v0, o0);
      o1 = mfma_bf16(pu.v, v1, o1);
    }
    sum += __shfl_xor(sum, 16);
    sum += __shfl_xor(sum, 32);
    const float rinv = 1.f / sum;
    #pragma unroll
    for (int j = 0; j < 4; ++j) {
      const int qa = mt * 16 + lg * 4 + j;
      const float rj = __shfl(rinv, lg * 4 + j);   // row sums live at lanes 0..15
      if (qa < 147) {
        const size_t base = (hb + qa) * 32;
        O[base + lr]      = (__bf16)(o0[j] * rj);
        O[base + 16 + lr] = (__bf16)(o1[j] * rj);
      }
    }
    qf = qn;
  }
}

extern "C" void kernel_launch(void* const* d_in, const int* in_sizes, int n_in,
                              void* d_out, int out_size, void* d_ws, size_t ws_size,
                              hipStream_t stream) {
  (void)in_sizes; (void)n_in; (void)out_size;
  const float* x_q  = (const float*)d_in[0];
  const float* x_k  = (const float*)d_in[1];
  const float* x_v  = (const float*)d_in[2];
  const float* maskp= (const float*)d_in[3];
  const float* q_w  = (const float*)d_in[4];
  const float* q_b  = (const float*)d_in[5];
  const float* k_w  = (const float*)d_in[6];
  const float* k_b  = (const float*)d_in[7];
  const float* v_w  = (const float*)d_in[8];
  const float* v_b  = (const float*)d_in[9];
  const float* p_w  = (const float*)d_in[10];
  const float* p_b  = (const float*)d_in[11];
  const float* btab = (const float*)d_in[12];

  char* ws = (char*)d_ws;
  // [bmw 12MB][4 weights][qb][kb][vb][ob?]
  float* bmw = (float*)ws;
  const size_t bmsz = (size_t)64 * 6 * 7840 * sizeof(float);   // 12,042,240
  char* wsp = ws + bmsz;
  const size_t wsz = 36864 * sizeof(__bf16);
  __bf16* wq  = (__bf16*)wsp;
  __bf16* wk  = (__bf16*)(wsp + wsz);
  __bf16* wvp = (__bf16*)(wsp + 2 * wsz);
  __bf16* wp  = (__bf16*)(wsp + 3 * wsz);
  char* bufs = wsp + 4 * wsz;
  const size_t sz = (size_t)ROWS * 192 * sizeof(__bf16);       // 57.8 MB each
  __bf16* qb = (__bf16*)bufs;
  __bf16* kb = (__bf16*)(bufs + sz);
  __bf16* vb = (__bf16*)(bufs + 2 * sz);
  const size_t need4 = bmsz + 4 * wsz + 4 * sz;
  __bf16* ob = (ws_size >= need4) ? (__bf16*)(bufs + 3 * sz) : qb;

  cvt4<<<dim3(36, 4), 256, 0, stream>>>(q_w, k_w, v_w, p_w, wq, wk, wvp, wp);
  bmpre<<<dim3(64, 6), 256, 0, stream>>>(maskp, btab, bmw);

  // q pre-scaled by 1/sqrt(hd) AND log2(e) (exp2-direct softmax downstream)
  gemmv3<true, false><<<ROWS / 64, 256, 0, stream>>>(x_q, wq, q_b, qb, QSCALE * L2E);
  gemmv3<true, false><<<ROWS / 64, 256, 0, stream>>>(x_k, wk, k_b, kb, 1.f);
  gemmv3<true, false><<<ROWS / 64, 256, 0, stream>>>(x_v, wvp, v_b, vb, 1.f);

  attn7<<<dim3(1024, 6), 256, 0, stream>>>(qb, kb, vb, ob, bmw);

  gemmv3<false, true><<<ROWS / 64, 256, 0, stream>>>(ob, wp, p_b, d_out, 1.f);
}